// Round 3
// baseline (174.600 us; speedup 1.0000x reference)
//
#include <hip/hip_runtime.h>
#include <hip/hip_bf16.h>
#include <stdint.h>

#define NS_ 4096
#define M_  8192
#define D_  256
#define TEMP 0.07f
#define EXP_SCALE 20.61707212818536f   // log2(e)/0.07 : exp(sim/T) = exp2(sim*EXP_SCALE)
#define LN2 0.6931471805599453f

typedef short bf16x8 __attribute__((ext_vector_type(8)));
typedef float f32x4  __attribute__((ext_vector_type(4)));
typedef unsigned short ushortx4 __attribute__((ext_vector_type(4)));

static __device__ inline unsigned short f2bf(float x) {
    unsigned u = __float_as_uint(x);
    u += 0x7fffu + ((u >> 16) & 1u);
    return (unsigned short)(u >> 16);
}

static __device__ inline float cleanf(float v) {
    return __builtin_isfinite(v) ? v : 0.0f;
}

// async 16B global -> LDS (lane-contiguous LDS destination required)
#define LDS_LOAD16(gp, lp) \
    __builtin_amdgcn_global_load_lds((const __attribute__((address_space(1))) uint32_t*)(gp), \
                                     (__attribute__((address_space(3))) uint32_t*)(lp), 16, 0, 0)

// ---------------- Kernel 1: clean + L2-normalize rows -> bf16 F; pos term -> out ---------
// grid = NS_, block = 64 (one wave per paired row)
__global__ __launch_bounds__(64) void knorm(const float* __restrict__ z1,
                                            const float* __restrict__ z2,
                                            short* __restrict__ F,
                                            float* __restrict__ out) {
    const int i = blockIdx.x;
    const int t = threadIdx.x;
    const float4* p1 = (const float4*)(z1 + (size_t)i * D_);
    const float4* p2 = (const float4*)(z2 + (size_t)i * D_);
    float4 a = p1[t], b = p2[t];
    a.x = cleanf(a.x); a.y = cleanf(a.y); a.z = cleanf(a.z); a.w = cleanf(a.w);
    b.x = cleanf(b.x); b.y = cleanf(b.y); b.z = cleanf(b.z); b.w = cleanf(b.w);

    float s1 = a.x*a.x + a.y*a.y + a.z*a.z + a.w*a.w;
    float s2 = b.x*b.x + b.y*b.y + b.z*b.z + b.w*b.w;
    float dp = a.x*b.x + a.y*b.y + a.z*b.z + a.w*b.w;
    #pragma unroll
    for (int m = 1; m < 64; m <<= 1) {
        s1 += __shfl_xor(s1, m);
        s2 += __shfl_xor(s2, m);
        dp += __shfl_xor(dp, m);
    }
    const float inv1 = 1.0f / fmaxf(sqrtf(s1), 1e-12f);
    const float inv2 = 1.0f / fmaxf(sqrtf(s2), 1e-12f);

    ushortx4 o1, o2;
    o1.x = f2bf(a.x * inv1); o1.y = f2bf(a.y * inv1); o1.z = f2bf(a.z * inv1); o1.w = f2bf(a.w * inv1);
    o2.x = f2bf(b.x * inv2); o2.y = f2bf(b.y * inv2); o2.z = f2bf(b.z * inv2); o2.w = f2bf(b.w * inv2);
    ((ushortx4*)(F + (size_t)i * D_))[t]          = o1;
    ((ushortx4*)(F + (size_t)(i + NS_) * D_))[t]  = o2;

    // loss contribution: -2 * pos_i / (T * M)
    if (t == 0) atomicAdd(out, dp * inv1 * inv2 * (-2.0f / (TEMP * (float)M_)));
}

// ---------------- Kernel 2: fused sim-GEMM + row sum(exp(sim/T)) + per-rtile log finisher
// grid = 512 = 128 rtiles x 4 col-quarters. Block: 64 rows x 2048 cols, K=256 resident.
// A: 4 strips x 8 ks bf16x8 persistent in VGPRs (128 VGPRs). B: 64-col tiles staged to LDS
// via global_load_lds with XOR-swizzled chunk order (swizzle applied on the GLOBAL address
// side since the LDS destination must be lane-contiguous). Each bfrag read feeds 4 MFMAs.
__global__ __launch_bounds__(256, 2) void kgemm(const short* __restrict__ F,
                                                float* __restrict__ denom,
                                                int* __restrict__ cnt,
                                                float* __restrict__ out) {
    __shared__ short Bl[64 * 256];   // 32 KB: [tile_col][k], 16B chunks XOR-swizzled by col
    __shared__ int lastflag;

    const int rtile = blockIdx.x >> 2;
    const int cq    = blockIdx.x & 3;
    const int R0 = rtile * 64;
    const int C0 = cq * 2048;

    const int tid  = threadIdx.x;
    const int lane = tid & 63;
    const int wave = tid >> 6;
    const int c16  = lane & 15;
    const int quad = lane >> 4;

    // Persistent A fragments: rows R0 + s*16 + c16, k = ks*32 + quad*8 + [0..8)
    bf16x8 afrag[4][8];
    #pragma unroll
    for (int s = 0; s < 4; ++s) {
        const short* ap = F + (size_t)(R0 + s * 16 + c16) * D_ + quad * 8;
        #pragma unroll
        for (int ks = 0; ks < 8; ++ks)
            afrag[s][ks] = *(const bf16x8*)(ap + ks * 32);
    }

    // staging: chunk c = tid + r2*256 -> LDS byte c*16; global chunk xor-swizzled
    int goff[8];
    #pragma unroll
    for (int r2 = 0; r2 < 8; ++r2) {
        int c    = tid + r2 * 256;
        int trow = c >> 5;
        int kg   = (c & 31) ^ (trow & 7);
        goff[r2] = trow * D_ + kg * 8;          // in shorts
    }
    // bfrag read offsets (it-independent): col tc, chunk (ks*4+quad)^(tc&7)
    const int tc = wave * 16 + c16;
    int boff[8];
    #pragma unroll
    for (int ks = 0; ks < 8; ++ks)
        boff[ks] = tc * 256 + (((ks * 4 + quad) ^ (tc & 7)) * 8);

    float accexp[4][4];
    #pragma unroll
    for (int s = 0; s < 4; ++s)
        #pragma unroll
        for (int r = 0; r < 4; ++r) accexp[s][r] = 0.0f;

    for (int it = 0; it < 32; ++it) {
        __syncthreads();                         // previous tile's reads done
        const short* gb = F + (size_t)(C0 + it * 64) * D_;
        #pragma unroll
        for (int r2 = 0; r2 < 8; ++r2)
            LDS_LOAD16(gb + goff[r2], Bl + (tid + r2 * 256) * 8);
        __syncthreads();                         // staging complete (vmcnt drained)

        bf16x8 bfrag[8];
        #pragma unroll
        for (int ks = 0; ks < 8; ++ks)
            bfrag[ks] = *(const bf16x8*)(Bl + boff[ks]);

        f32x4 acc[4];
        #pragma unroll
        for (int s = 0; s < 4; ++s) acc[s] = (f32x4){0.f, 0.f, 0.f, 0.f};
        #pragma unroll
        for (int ks = 0; ks < 8; ++ks)
            #pragma unroll
            for (int s = 0; s < 4; ++s)
                acc[s] = __builtin_amdgcn_mfma_f32_16x16x32_bf16(afrag[s][ks], bfrag[ks], acc[s], 0, 0, 0);

        const int colbase = C0 + it * 64 + wave * 16;   // wave-uniform
        #pragma unroll
        for (int s = 0; s < 4; ++s) {
            if (colbase != R0 + s * 16) {                // fast path (uniform branch)
                #pragma unroll
                for (int r = 0; r < 4; ++r)
                    accexp[s][r] += __builtin_amdgcn_exp2f(acc[s][r] * EXP_SCALE);
            } else {                                     // diagonal tile: mask row==col
                #pragma unroll
                for (int r = 0; r < 4; ++r) {
                    float e = __builtin_amdgcn_exp2f(acc[s][r] * EXP_SCALE);
                    if (c16 == quad * 4 + r) e = 0.0f;
                    accexp[s][r] += e;
                }
            }
        }
    }

    // reduce row sums across the 16 cols held by this wave's lanes, one atomic per row
    #pragma unroll
    for (int s = 0; s < 4; ++s)
        #pragma unroll
        for (int r = 0; r < 4; ++r) {
            float v = accexp[s][r];
            v += __shfl_xor(v, 1);
            v += __shfl_xor(v, 2);
            v += __shfl_xor(v, 4);
            v += __shfl_xor(v, 8);
            if (c16 == 0) atomicAdd(&denom[R0 + s * 16 + quad * 4 + r], v);
        }

    // last block for this rtile computes sum(log(denom[R0..R0+64))) / M -> out
    __syncthreads();
    if (tid == 0) {
        __threadfence();                                  // release our denom adds
        lastflag = (atomicAdd(&cnt[rtile], 1) == 3);
    }
    __syncthreads();
    if (lastflag && tid < 64) {
        __threadfence();                                  // acquire others' denom adds
        float v = atomicAdd(&denom[R0 + tid], 0.0f);      // device-scope coherent read
        float p = __builtin_amdgcn_logf(v) * (LN2 / (float)M_);
        #pragma unroll
        for (int m = 1; m < 64; m <<= 1) p += __shfl_xor(p, m);
        if (tid == 0) atomicAdd(out, p);
    }
}

extern "C" void kernel_launch(void* const* d_in, const int* in_sizes, int n_in,
                              void* d_out, int out_size, void* d_ws, size_t ws_size,
                              hipStream_t stream) {
    const float* z1 = (const float*)d_in[0];
    const float* z2 = (const float*)d_in[1];

    short* F     = (short*)d_ws;                                   // 4 MB
    float* denom = (float*)((char*)d_ws + (size_t)M_ * D_ * 2);    // 32 KB
    int*   cnt   = (int*)(denom + M_);                             // 512 B
    float* out   = (float*)d_out;

    hipMemsetAsync(denom, 0, M_ * sizeof(float) + 128 * sizeof(int), stream);
    hipMemsetAsync(out, 0, sizeof(float), stream);
    knorm<<<NS_, 64, 0, stream>>>(z1, z2, F, out);
    kgemm<<<512, 256, 0, stream>>>(F, denom, cnt, out);
}

// Round 4
// 139.920 us; speedup vs baseline: 1.2479x; 1.2479x over previous
//
#include <hip/hip_runtime.h>
#include <hip/hip_bf16.h>
#include <stdint.h>

#define NS_ 4096
#define M_  8192
#define D_  256
#define TEMP 0.07f
#define EXP_SCALE 20.61707212818536f   // log2(e)/0.07 : exp(sim/T) = exp2(sim*EXP_SCALE)
#define LN2 0.6931471805599453f

typedef short bf16x8 __attribute__((ext_vector_type(8)));
typedef float f32x4  __attribute__((ext_vector_type(4)));
typedef unsigned short ushortx4 __attribute__((ext_vector_type(4)));

static __device__ inline unsigned short f2bf(float x) {
    unsigned u = __float_as_uint(x);
    u += 0x7fffu + ((u >> 16) & 1u);
    return (unsigned short)(u >> 16);
}

static __device__ inline float cleanf(float v) {
    return __builtin_isfinite(v) ? v : 0.0f;
}

// ---------------- Kernel 1: clean + L2-normalize rows -> bf16 F; fp32 pos[] -------------
// grid = NS_, block = 64 (one wave per paired row)
__global__ __launch_bounds__(64) void knorm(const float* __restrict__ z1,
                                            const float* __restrict__ z2,
                                            short* __restrict__ F,
                                            float* __restrict__ pos,
                                            float* __restrict__ out) {
    const int i = blockIdx.x;
    const int t = threadIdx.x;
    const float4* p1 = (const float4*)(z1 + (size_t)i * D_);
    const float4* p2 = (const float4*)(z2 + (size_t)i * D_);
    float4 a = p1[t], b = p2[t];
    a.x = cleanf(a.x); a.y = cleanf(a.y); a.z = cleanf(a.z); a.w = cleanf(a.w);
    b.x = cleanf(b.x); b.y = cleanf(b.y); b.z = cleanf(b.z); b.w = cleanf(b.w);

    float s1 = a.x*a.x + a.y*a.y + a.z*a.z + a.w*a.w;
    float s2 = b.x*b.x + b.y*b.y + b.z*b.z + b.w*b.w;
    float dp = a.x*b.x + a.y*b.y + a.z*b.z + a.w*b.w;
    #pragma unroll
    for (int m = 1; m < 64; m <<= 1) {
        s1 += __shfl_xor(s1, m);
        s2 += __shfl_xor(s2, m);
        dp += __shfl_xor(dp, m);
    }
    const float inv1 = 1.0f / fmaxf(sqrtf(s1), 1e-12f);
    const float inv2 = 1.0f / fmaxf(sqrtf(s2), 1e-12f);

    ushortx4 o1, o2;
    o1.x = f2bf(a.x * inv1); o1.y = f2bf(a.y * inv1); o1.z = f2bf(a.z * inv1); o1.w = f2bf(a.w * inv1);
    o2.x = f2bf(b.x * inv2); o2.y = f2bf(b.y * inv2); o2.z = f2bf(b.z * inv2); o2.w = f2bf(b.w * inv2);
    ((ushortx4*)(F + (size_t)i * D_))[t]          = o1;
    ((ushortx4*)(F + (size_t)(i + NS_) * D_))[t]  = o2;

    if (t == 0) pos[i] = dp * inv1 * inv2;         // exact fp32 positive sim
    if (t == 0 && i == 0) out[0] = 0.0f;           // init accumulator (pre-kgemm)
}

// ---------------- Kernel 2: barrier-free fused sim-GEMM + row exp-sums + finishers ------
// grid = 512 = 128 rtiles x 4 col-quarters. Block: 64 rows x 2048 cols, K=256.
// A: 4 strips x 8 ks bf16x8 persistent in VGPRs. B: read DIRECTLY from global (L2-hot)
// as b128 fragments, 2-deep pipelined. NO LDS staging, NO barriers in the main loop.
#define BLOAD(dst, j) do {                                             \
    const short* _b = bp + (size_t)(j) * 16384;                        \
    _Pragma("unroll")                                                  \
    for (int _k = 0; _k < 8; ++_k)                                     \
        dst[_k] = *(const bf16x8*)(_b + _k * 32);                      \
} while (0)

#define COMPUTE(bb, j) do {                                            \
    f32x4 acc[4];                                                      \
    _Pragma("unroll")                                                  \
    for (int _s = 0; _s < 4; ++_s) acc[_s] = (f32x4){0.f,0.f,0.f,0.f}; \
    _Pragma("unroll")                                                  \
    for (int _k = 0; _k < 8; ++_k)                                     \
        _Pragma("unroll")                                              \
        for (int _s = 0; _s < 4; ++_s)                                 \
            acc[_s] = __builtin_amdgcn_mfma_f32_16x16x32_bf16(         \
                afrag[_s][_k], bb[_k], acc[_s], 0, 0, 0);              \
    const int colbase = C0 + (j) * 64 + wave * 16;                     \
    _Pragma("unroll")                                                  \
    for (int _s = 0; _s < 4; ++_s) {                                   \
        if (colbase != R0 + _s * 16) {                                 \
            _Pragma("unroll")                                          \
            for (int _r = 0; _r < 4; ++_r)                             \
                accexp[_s][_r] +=                                      \
                    __builtin_amdgcn_exp2f(acc[_s][_r] * EXP_SCALE);   \
        } else {                                                       \
            _Pragma("unroll")                                          \
            for (int _r = 0; _r < 4; ++_r) {                           \
                float _e =                                             \
                    __builtin_amdgcn_exp2f(acc[_s][_r] * EXP_SCALE);   \
                if (c16 == quad * 4 + _r) _e = 0.0f;                   \
                accexp[_s][_r] += _e;                                  \
            }                                                          \
        }                                                              \
    }                                                                  \
} while (0)

__global__ __launch_bounds__(256, 2) void kgemm(const short* __restrict__ F,
                                                float* __restrict__ denom,
                                                int* __restrict__ cnt,
                                                const float* __restrict__ pos,
                                                float* __restrict__ out) {
    __shared__ int lastflag;
    __shared__ float redP[4];

    const int rtile = blockIdx.x >> 2;
    const int cq    = blockIdx.x & 3;
    const int R0 = rtile * 64;
    const int C0 = cq * 2048;

    const int tid  = threadIdx.x;
    const int lane = tid & 63;
    const int wave = tid >> 6;
    const int c16  = lane & 15;
    const int quad = lane >> 4;

    // Persistent A fragments: rows R0 + s*16 + c16, k = ks*32 + quad*8 + [0..8)
    bf16x8 afrag[4][8];
    #pragma unroll
    for (int s = 0; s < 4; ++s) {
        const short* ap = F + (size_t)(R0 + s * 16 + c16) * D_ + quad * 8;
        #pragma unroll
        for (int ks = 0; ks < 8; ++ks)
            afrag[s][ks] = *(const bf16x8*)(ap + ks * 32);
    }

    float accexp[4][4];
    #pragma unroll
    for (int s = 0; s < 4; ++s)
        #pragma unroll
        for (int r = 0; r < 4; ++r) accexp[s][r] = 0.0f;

    // B fragment base for this lane: col C0 + wave*16 + c16, k-offset quad*8
    const short* bp = F + (size_t)(C0 + wave * 16 + c16) * D_ + quad * 8;

    // 2-deep pipelined main loop over 32 column groups of 64
    bf16x8 b0[8], b1[8];
    BLOAD(b0, 0);
    for (int j = 0; j < 32; j += 2) {
        BLOAD(b1, j + 1);
        COMPUTE(b0, j);
        if (j + 2 < 32) BLOAD(b0, j + 2);
        COMPUTE(b1, j + 1);
    }

    // reduce row sums across the 16 cols held by this wave's lanes, one atomic per row
    #pragma unroll
    for (int s = 0; s < 4; ++s)
        #pragma unroll
        for (int r = 0; r < 4; ++r) {
            float v = accexp[s][r];
            v += __shfl_xor(v, 1);
            v += __shfl_xor(v, 2);
            v += __shfl_xor(v, 4);
            v += __shfl_xor(v, 8);
            if (c16 == 0) atomicAdd(&denom[R0 + s * 16 + quad * 4 + r], v);
        }

    // last block per rtile: sum(log(denom[R0..R0+64))) / M -> out; rtile 0 also adds pos
    __syncthreads();
    if (tid == 0) {
        __threadfence();                                  // release our denom adds
        lastflag = (atomicAdd(&cnt[rtile], 1) == 3);
    }
    __syncthreads();
    if (lastflag) {
        if (tid < 64) {
            __threadfence();                              // acquire others' denom adds
            float v = atomicAdd(&denom[R0 + tid], 0.0f);  // device-scope coherent read
            float p = __builtin_amdgcn_logf(v) * (LN2 / (float)M_);
            #pragma unroll
            for (int m = 1; m < 64; m <<= 1) p += __shfl_xor(p, m);
            if (tid == 0) atomicAdd(out, p);
        }
        if (rtile == 0) {                                 // pos ready since knorm finished
            float sp = 0.0f;
            for (int i = tid; i < NS_; i += 256) sp += pos[i];
            #pragma unroll
            for (int m = 1; m < 64; m <<= 1) sp += __shfl_xor(sp, m);
            if (lane == 0) redP[wave] = sp;
            __syncthreads();
            if (tid == 0)
                atomicAdd(out, (redP[0] + redP[1] + redP[2] + redP[3]) *
                               (-2.0f / (TEMP * (float)M_)));
        }
    }
}

extern "C" void kernel_launch(void* const* d_in, const int* in_sizes, int n_in,
                              void* d_out, int out_size, void* d_ws, size_t ws_size,
                              hipStream_t stream) {
    const float* z1 = (const float*)d_in[0];
    const float* z2 = (const float*)d_in[1];

    short* F     = (short*)d_ws;                                   // 4 MB
    float* denom = (float*)((char*)d_ws + (size_t)M_ * D_ * 2);    // 32 KB
    int*   cnt   = (int*)(denom + M_);                             // 512 B
    float* pos   = (float*)(cnt + 128);                            // 16 KB
    float* out   = (float*)d_out;

    // zero denom + cnt in one shot (33280 B)
    hipMemsetAsync(denom, 0, M_ * sizeof(float) + 128 * sizeof(int), stream);
    knorm<<<NS_, 64, 0, stream>>>(z1, z2, F, pos, out);
    kgemm<<<512, 256, 0, stream>>>(F, denom, cnt, pos, out);
}

// Round 5
// 109.095 us; speedup vs baseline: 1.6004x; 1.2826x over previous
//
#include <hip/hip_runtime.h>
#include <hip/hip_bf16.h>
#include <stdint.h>

#define NS_ 4096
#define M_  8192
#define D_  256
#define TEMP 0.07f
#define EXP_SCALE 20.61707212818536f   // log2(e)/0.07 : exp(sim/T) = exp2(sim*EXP_SCALE)
#define LN2 0.6931471805599453f

typedef short bf16x8 __attribute__((ext_vector_type(8)));
typedef float f32x4  __attribute__((ext_vector_type(4)));
typedef unsigned short ushortx4 __attribute__((ext_vector_type(4)));

static __device__ inline unsigned short f2bf(float x) {
    unsigned u = __float_as_uint(x);
    u += 0x7fffu + ((u >> 16) & 1u);
    return (unsigned short)(u >> 16);
}

static __device__ inline float cleanf(float v) {
    return __builtin_isfinite(v) ? v : 0.0f;
}

// async 16B global -> LDS (lane-contiguous LDS destination required)
#define LDS_LOAD16(gp, lp) \
    __builtin_amdgcn_global_load_lds((const __attribute__((address_space(1))) uint32_t*)(gp), \
                                     (__attribute__((address_space(3))) uint32_t*)(lp), 16, 0, 0)

// ---------------- Kernel 1: clean + normalize -> bf16 F, fp32 pos[]; zero denom/cnt/out -
// grid = NS_, block = 64 (one wave per paired row)
__global__ __launch_bounds__(64) void knorm(const float* __restrict__ z1,
                                            const float* __restrict__ z2,
                                            short* __restrict__ F,
                                            float* __restrict__ pos,
                                            float* __restrict__ denom,
                                            int* __restrict__ cnt,
                                            float* __restrict__ out) {
    const int i = blockIdx.x;
    const int t = threadIdx.x;
    const float4* p1 = (const float4*)(z1 + (size_t)i * D_);
    const float4* p2 = (const float4*)(z2 + (size_t)i * D_);
    float4 a = p1[t], b = p2[t];
    a.x = cleanf(a.x); a.y = cleanf(a.y); a.z = cleanf(a.z); a.w = cleanf(a.w);
    b.x = cleanf(b.x); b.y = cleanf(b.y); b.z = cleanf(b.z); b.w = cleanf(b.w);

    float s1 = a.x*a.x + a.y*a.y + a.z*a.z + a.w*a.w;
    float s2 = b.x*b.x + b.y*b.y + b.z*b.z + b.w*b.w;
    float dp = a.x*b.x + a.y*b.y + a.z*b.z + a.w*b.w;
    #pragma unroll
    for (int m = 1; m < 64; m <<= 1) {
        s1 += __shfl_xor(s1, m);
        s2 += __shfl_xor(s2, m);
        dp += __shfl_xor(dp, m);
    }
    const float inv1 = 1.0f / fmaxf(sqrtf(s1), 1e-12f);
    const float inv2 = 1.0f / fmaxf(sqrtf(s2), 1e-12f);

    ushortx4 o1, o2;
    o1.x = f2bf(a.x * inv1); o1.y = f2bf(a.y * inv1); o1.z = f2bf(a.z * inv1); o1.w = f2bf(a.w * inv1);
    o2.x = f2bf(b.x * inv2); o2.y = f2bf(b.y * inv2); o2.z = f2bf(b.z * inv2); o2.w = f2bf(b.w * inv2);
    ((ushortx4*)(F + (size_t)i * D_))[t]          = o1;
    ((ushortx4*)(F + (size_t)(i + NS_) * D_))[t]  = o2;

    if (t == 0) pos[i] = dp * inv1 * inv2;       // exact fp32 positive sim
    if (t < 2)  denom[i * 2 + t] = 0.0f;         // zero denom (2 per block x 4096)
    if (i == 0 && t < 32) cnt[t] = 0;            // zero rtile counters
    if (i == 0 && t == 0) out[0] = 0.0f;         // zero loss accumulator
}

// ---------------- Kernel 2: fused sim-GEMM + row exp-sums + finishers -------------------
// grid = 512 = 32 rtiles (256 rows) x 16 col-blocks (512 cols). 256 thr / 4 waves.
// Wave w owns 4 row-strips: rows R0 + ch*64 + w*16 (ch=0..3), A-frags K=256 resident
// (128 VGPR). A staged via LDS in 4 coalesced 64-row chunks (prologue). B: 8 groups of
// 64 cols staged via global_load_lds, XOR-swizzled; each staged tile feeds 128 MFMAs/wave.
__global__ __launch_bounds__(256, 2) void kgemm(const short* __restrict__ F,
                                                float* __restrict__ denom,
                                                int* __restrict__ cnt,
                                                const float* __restrict__ pos,
                                                float* __restrict__ out) {
    __shared__ short Bl[64 * 256];   // 32 KB staging tile [row][k], 16B chunks swizzled
    __shared__ int lastflag;
    __shared__ float red[4];

    const int rtile = blockIdx.x >> 4;   // 32 rtiles
    const int cq    = blockIdx.x & 15;   // 16 col-blocks
    const int R0 = rtile * 256;
    const int C0 = cq * 512;

    const int tid  = threadIdx.x;
    const int lane = tid & 63;
    const int wave = tid >> 6;
    const int c16  = lane & 15;
    const int quad = lane >> 4;
    const int swz  = c16 & 7;

    // staging source offsets (shorts, relative to 64-row chunk base), XOR-swizzled
    int goff[8];
    #pragma unroll
    for (int r2 = 0; r2 < 8; ++r2) {
        int c    = tid + r2 * 256;
        int row  = c >> 5;
        int kg   = (c & 31) ^ (row & 7);
        goff[r2] = row * D_ + kg * 8;
    }

    // ---- A prologue: 4 chunks of 64 rows; wave w reads local rows w*16+c16 of each chunk
    bf16x8 afrag[4][8];
    const int arow_l = wave * 16 + c16;
    #pragma unroll
    for (int ch = 0; ch < 4; ++ch) {
        __syncthreads();
        const short* ga = F + (size_t)(R0 + ch * 64) * D_;
        #pragma unroll
        for (int r2 = 0; r2 < 8; ++r2)
            LDS_LOAD16(ga + goff[r2], Bl + (tid + r2 * 256) * 8);
        __syncthreads();
        #pragma unroll
        for (int ks = 0; ks < 8; ++ks)
            afrag[ch][ks] = *(const bf16x8*)(Bl + arow_l * 256 +
                                             (((ks * 4 + quad) ^ (arow_l & 7)) * 8));
    }

    float accexp[4][4];
    #pragma unroll
    for (int s = 0; s < 4; ++s)
        #pragma unroll
        for (int r = 0; r < 4; ++r) accexp[s][r] = 0.0f;

    // ---- main loop: 8 B-groups of 64 cols
    for (int it = 0; it < 8; ++it) {
        __syncthreads();                       // previous tile's reads done
        const short* gb = F + (size_t)(C0 + it * 64) * D_;
        #pragma unroll
        for (int r2 = 0; r2 < 8; ++r2)
            LDS_LOAD16(gb + goff[r2], Bl + (tid + r2 * 256) * 8);
        __syncthreads();                       // staging complete

        #pragma unroll
        for (int sub = 0; sub < 4; ++sub) {
            const int tc = sub * 16 + c16;     // tile col owned by this lane
            bf16x8 bfrag[8];
            #pragma unroll
            for (int ks = 0; ks < 8; ++ks)
                bfrag[ks] = *(const bf16x8*)(Bl + tc * 256 +
                                             (((ks * 4 + quad) ^ swz) * 8));
            f32x4 acc[4];
            #pragma unroll
            for (int s = 0; s < 4; ++s) acc[s] = (f32x4){0.f, 0.f, 0.f, 0.f};
            #pragma unroll
            for (int ks = 0; ks < 8; ++ks)
                #pragma unroll
                for (int s = 0; s < 4; ++s)
                    acc[s] = __builtin_amdgcn_mfma_f32_16x16x32_bf16(
                        afrag[s][ks], bfrag[ks], acc[s], 0, 0, 0);

            const int colbase = C0 + it * 64 + sub * 16;
            #pragma unroll
            for (int s = 0; s < 4; ++s) {
                const int rowbase = R0 + s * 64 + wave * 16;
                if (colbase != rowbase) {            // uniform fast path
                    #pragma unroll
                    for (int r = 0; r < 4; ++r)
                        accexp[s][r] += __builtin_amdgcn_exp2f(acc[s][r] * EXP_SCALE);
                } else {                             // diagonal 16x16 tile
                    #pragma unroll
                    for (int r = 0; r < 4; ++r) {
                        float e = __builtin_amdgcn_exp2f(acc[s][r] * EXP_SCALE);
                        if (c16 == quad * 4 + r) e = 0.0f;
                        accexp[s][r] += e;
                    }
                }
            }
        }
    }

    // row sums across the 16 lanes holding each row, one atomic per row
    #pragma unroll
    for (int s = 0; s < 4; ++s)
        #pragma unroll
        for (int r = 0; r < 4; ++r) {
            float v = accexp[s][r];
            v += __shfl_xor(v, 1);
            v += __shfl_xor(v, 2);
            v += __shfl_xor(v, 4);
            v += __shfl_xor(v, 8);
            if (c16 == 0)
                atomicAdd(&denom[R0 + s * 64 + wave * 16 + quad * 4 + r], v);
        }

    // last of 16 blocks per rtile: sum(log(denom[R0..R0+256))) / M -> out (+ pos term)
    __syncthreads();
    if (tid == 0) {
        __threadfence();                              // release our denom adds
        lastflag = (atomicAdd(&cnt[rtile], 1) == 15);
    }
    __syncthreads();
    if (lastflag) {
        __threadfence();                              // acquire others' denom adds
        float v = atomicAdd(&denom[R0 + tid], 0.0f);  // coherent read, 256 rows
        float p = __builtin_amdgcn_logf(v) * (LN2 / (float)M_);
        #pragma unroll
        for (int m = 1; m < 64; m <<= 1) p += __shfl_xor(p, m);
        if (lane == 0) red[wave] = p;
        __syncthreads();
        if (tid == 0) atomicAdd(out, red[0] + red[1] + red[2] + red[3]);
        if (rtile == 0) {                             // pos ready (knorm precedes)
            __syncthreads();                          // protect red reuse
            float sp = 0.0f;
            for (int i = tid; i < NS_; i += 256) sp += pos[i];
            #pragma unroll
            for (int m = 1; m < 64; m <<= 1) sp += __shfl_xor(sp, m);
            if (lane == 0) red[wave] = sp;
            __syncthreads();
            if (tid == 0)
                atomicAdd(out, (red[0] + red[1] + red[2] + red[3]) *
                               (-2.0f / (TEMP * (float)M_)));
        }
    }
}

extern "C" void kernel_launch(void* const* d_in, const int* in_sizes, int n_in,
                              void* d_out, int out_size, void* d_ws, size_t ws_size,
                              hipStream_t stream) {
    const float* z1 = (const float*)d_in[0];
    const float* z2 = (const float*)d_in[1];

    short* F     = (short*)d_ws;                                   // 4 MB
    float* denom = (float*)((char*)d_ws + (size_t)M_ * D_ * 2);    // 32 KB
    int*   cnt   = (int*)(denom + M_);                             // 128 B
    float* pos   = (float*)(cnt + 32);                             // 16 KB
    float* out   = (float*)d_out;

    knorm<<<NS_, 64, 0, stream>>>(z1, z2, F, pos, denom, cnt, out);
    kgemm<<<512, 256, 0, stream>>>(F, denom, cnt, pos, out);
}